// Round 9
// baseline (201.166 us; speedup 1.0000x reference)
//
#include <hip/hip_runtime.h>
#include <stdint.h>

// B=2, S=2048, D=1024, H=16, dh=64, THETA=10000
// cast3 -> QKV gemm (XCD-swizzled, LDS-staged rope/vtrans epilogue) ->
// flash attn (persistent blocks + atomic work-stealing, BQ=64, S^T, reg-PV) -> out gemm

typedef __attribute__((ext_vector_type(8))) __bf16 bf16x8;
typedef __attribute__((ext_vector_type(8))) unsigned short u16x8;
typedef __attribute__((ext_vector_type(4))) float f32x4;

__device__ __forceinline__ unsigned short f2bf(float f){
  unsigned int u = __float_as_uint(f);
  unsigned int r = (u + 0x7FFFu + ((u >> 16) & 1u)) >> 16;  // RNE
  return (unsigned short)r;
}
__device__ __forceinline__ float bf2f(unsigned short u){
  return __uint_as_float(((unsigned int)u) << 16);
}
// pack two fp32 -> two bf16 (truncate) in one v_perm_b32
__device__ __forceinline__ unsigned int pack_bf2(float lo, float hi){
  return __builtin_amdgcn_perm(__float_as_uint(hi), __float_as_uint(lo), 0x07060302u);
}

// async global->LDS, 16B per lane; LDS dest = wave-uniform base + lane*16
__device__ __forceinline__ void gld16(const unsigned short* g, unsigned short* l){
  __builtin_amdgcn_global_load_lds((const __attribute__((address_space(1))) unsigned int*)g,
                                   (__attribute__((address_space(3))) unsigned int*)l,
                                   16, 0, 0);
}

__global__ __launch_bounds__(256) void cast3_kernel(const float* __restrict__ a,
                                                    const float* __restrict__ b,
                                                    const float* __restrict__ c,
                                                    unsigned short* __restrict__ oa,
                                                    unsigned short* __restrict__ ob,
                                                    unsigned short* __restrict__ oc,
                                                    int na, int nb){
  int i = blockIdx.x * 256 + threadIdx.x;
  const float* in; unsigned short* out; int j = i;
  if (i < na){ in = a; out = oa; }
  else if (i < na + nb){ in = b; out = ob; j = i - na; }
  else { in = c; out = oc; j = i - na - nb; }
  float4 v = ((const float4*)in)[j];
  ushort4 o;
  o.x = f2bf(v.x); o.y = f2bf(v.y); o.z = f2bf(v.z); o.w = f2bf(v.w);
  ((ushort4*)out)[j] = o;
}

// QKV = X * Wqkv^T, 128x128 tile, BK=64, async-LDS, XOR swizzle.
// Grid: 768 blocks 1D; xcd = bx&7 owns n-tiles {3*xcd..3*xcd+2} (W hot in per-XCD L2).
__global__ __launch_bounds__(256) void gemm_qkv(const unsigned short* __restrict__ A,
                                                const unsigned short* __restrict__ W,
                                                unsigned short* __restrict__ Qh,
                                                unsigned short* __restrict__ Kh,
                                                unsigned short* __restrict__ Vtp){
  __shared__ __align__(16) unsigned short As[128*64];
  __shared__ __align__(16) unsigned short Bs[128*64];
  const int K = 1024;
  const int tid  = threadIdx.x;
  const int lane = tid & 63, wave = tid >> 6;
  const int wr = wave >> 1, wc = wave & 1;
  const int quad = lane >> 4, c = lane & 15;
  const int bx = blockIdx.x;
  const int xcd = bx & 7, kk = bx >> 3;       // kk in [0,96)
  const int n0 = (xcd*3 + (kk % 3)) * 128;
  const int m0 = (kk / 3) * 128;

  const f32x4 z4 = {0.f, 0.f, 0.f, 0.f};
  f32x4 acc[4][4];
  #pragma unroll
  for (int i = 0; i < 4; i++)
    #pragma unroll
    for (int j = 0; j < 4; j++) acc[i][j] = z4;

  for (int kt = 0; kt < 16; kt++){
    const int k0 = kt << 6;
    #pragma unroll
    for (int p = 0; p < 4; p++){
      int blk = p*4 + wave;
      int L = blk*64 + lane;
      int row = L >> 3;
      int sub = (L & 7) ^ (row & 7);
      gld16(&A[(size_t)(m0+row)*K + k0 + sub*8], &As[blk*512]);
      gld16(&W[(size_t)(n0+row)*K + k0 + sub*8], &Bs[blk*512]);
    }
    __syncthreads();
    #pragma unroll
    for (int ks = 0; ks < 2; ks++){
      bf16x8 af[4], bfr[4];
      #pragma unroll
      for (int i = 0; i < 4; i++){
        int row = wr*64 + i*16 + c;
        int pos = (ks*4 + quad) ^ (c & 7);
        af[i] = *(const bf16x8*)&As[row*64 + pos*8];
      }
      #pragma unroll
      for (int j = 0; j < 4; j++){
        int row = wc*64 + j*16 + c;
        int pos = (ks*4 + quad) ^ (c & 7);
        bfr[j] = *(const bf16x8*)&Bs[row*64 + pos*8];
      }
      #pragma unroll
      for (int i = 0; i < 4; i++)
        #pragma unroll
        for (int j = 0; j < 4; j++)
          acc[i][j] = __builtin_amdgcn_mfma_f32_16x16x32_bf16(af[i], bfr[j], acc[i][j], 0, 0, 0);
    }
    __syncthreads();
  }

  const int t  = n0 >> 10;            // 0=Q 1=K 2=V (block-uniform)
  const int h0 = (n0 & 1023) >> 6;
  const int bb = m0 >> 11;            // batch (tile never crosses the boundary)
  const int s0 = m0 & 2047;

  // stage C tile (each wave-column's 64 cols) into LDS, bf16, xor-swizzled
  unsigned short* stg = wc ? Bs : As;
  #pragma unroll
  for (int i = 0; i < 4; i++)
    #pragma unroll
    for (int j = 0; j < 4; j++)
      #pragma unroll
      for (int r = 0; r < 4; r++){
        int sl = wr*64 + i*16 + quad*4 + r;
        int d  = j*16 + c;
        stg[sl*64 + (d ^ ((sl & 7) << 3))] = f2bf(acc[i][j][r]);
      }
  __syncthreads();

  if (t < 2){
    // rope at readout: lane holds 8 consecutive d = 4 (even,odd) pairs in-register
    unsigned short* dst = (t == 0) ? Qh : Kh;
    const float qs = (t == 0) ? 0.18033688011112042f : 1.0f;   // log2(e)/8 into Q
    #pragma unroll
    for (int it = 0; it < 8; it++){
      int cidx2 = it*256 + tid;            // hh(2) x sl(128) x sub(8)
      int hh = cidx2 >> 10, cidx = cidx2 & 1023;
      int sl = cidx >> 3, sub = cidx & 7;
      const unsigned short* src = hh ? Bs : As;
      u16x8 pk = *(const u16x8*)&src[sl*64 + ((sub*8) ^ ((sl & 7) << 3))];
      int s = s0 + sl;
      u16x8 o;
      #pragma unroll
      for (int tp = 0; tp < 4; tp++){
        int p = sub*4 + tp;
        float freq = __expf(-(float)p * 0.28782313662425572f);  // theta^(-p/32)
        float ang = (float)s * freq;
        float sn, cs;
        __sincosf(ang, &sn, &cs);
        float e = bf2f(pk[2*tp]), od = bf2f(pk[2*tp+1]);
        o[2*tp]   = f2bf((e*cs - od*sn) * qs);
        o[2*tp+1] = f2bf((e*sn + od*cs) * qs);
      }
      *(u16x8*)&dst[(size_t)((h0 + hh)*2 + bb)*2048*64 + (size_t)s*64 + sub*8] = o;
    }
  } else {
    // V: transpose + pi-permute -> Vtp [h][b][d][S]
    #pragma unroll
    for (int it = 0; it < 8; it++){
      int cidx2 = it*256 + tid;             // hh(2) x d(64) x g8(16)
      int hh = cidx2 >> 10, cidx = cidx2 & 1023;
      int d = cidx >> 4, g8 = cidx & 15;
      int C = g8 >> 2, q8 = g8 & 3;
      const unsigned short* src = hh ? Bs : As;
      u16x8 pk;
      #pragma unroll
      for (int jj = 0; jj < 8; jj++){
        int r = C*32 + ((jj >> 2) << 4) + q8*4 + (jj & 3);   // pi
        pk[jj] = src[r*64 + (d ^ ((r & 7) << 3))];
      }
      size_t obase = (size_t)(((h0 + hh)*2 + bb) * 64) * 2048;
      *(u16x8*)&Vtp[obase + (size_t)d*2048 + s0 + g8*8] = pk;
    }
  }
}

// out gemm: 64M x 128N tile, fp32 out. xcd = bx&7 owns n-tile bx&7; m = bx>>3.
__global__ __launch_bounds__(256) void gemm_o(const unsigned short* __restrict__ A,
                                              const unsigned short* __restrict__ W,
                                              float* __restrict__ Cp,
                                              int M, int N, int K){
  __shared__ __align__(16) unsigned short As[64*64];
  __shared__ __align__(16) unsigned short Bs[128*64];
  const int tid  = threadIdx.x;
  const int lane = tid & 63, wave = tid >> 6;
  const int wr = wave >> 1, wc = wave & 1;
  const int quad = lane >> 4, c = lane & 15;
  const int m0 = (blockIdx.x >> 3) * 64, n0 = (blockIdx.x & 7) * 128;

  const f32x4 z4 = {0.f, 0.f, 0.f, 0.f};
  f32x4 acc[2][4];
  #pragma unroll
  for (int i = 0; i < 2; i++)
    #pragma unroll
    for (int j = 0; j < 4; j++) acc[i][j] = z4;

  const int nk = K >> 6;
  for (int kt = 0; kt < nk; kt++){
    const int k0 = kt << 6;
    #pragma unroll
    for (int p = 0; p < 2; p++){
      int blk = p*4 + wave;
      int L = blk*64 + lane;
      int row = L >> 3;
      int sub = (L & 7) ^ (row & 7);
      gld16(&A[(size_t)(m0+row)*K + k0 + sub*8], &As[blk*512]);
    }
    #pragma unroll
    for (int p = 0; p < 4; p++){
      int blk = p*4 + wave;
      int L = blk*64 + lane;
      int row = L >> 3;
      int sub = (L & 7) ^ (row & 7);
      gld16(&W[(size_t)(n0+row)*K + k0 + sub*8], &Bs[blk*512]);
    }
    __syncthreads();
    #pragma unroll
    for (int ks = 0; ks < 2; ks++){
      bf16x8 af[2], bfr[4];
      #pragma unroll
      for (int i = 0; i < 2; i++){
        int row = wr*32 + i*16 + c;
        int pos = (ks*4 + quad) ^ (c & 7);
        af[i] = *(const bf16x8*)&As[row*64 + pos*8];
      }
      #pragma unroll
      for (int j = 0; j < 4; j++){
        int row = wc*64 + j*16 + c;
        int pos = (ks*4 + quad) ^ (c & 7);
        bfr[j] = *(const bf16x8*)&Bs[row*64 + pos*8];
      }
      #pragma unroll
      for (int i = 0; i < 2; i++)
        #pragma unroll
        for (int j = 0; j < 4; j++)
          acc[i][j] = __builtin_amdgcn_mfma_f32_16x16x32_bf16(af[i], bfr[j], acc[i][j], 0, 0, 0);
    }
    __syncthreads();
  }
  #pragma unroll
  for (int i = 0; i < 2; i++)
    #pragma unroll
    for (int j = 0; j < 4; j++)
      #pragma unroll
      for (int r = 0; r < 4; r++){
        int row = m0 + wr*32 + i*16 + quad*4 + r;
        int col = n0 + wc*64 + j*16 + c;
        Cp[(size_t)row*N + col] = acc[i][j][r];
      }
}

// Flash attention, causal, S^T, persistent blocks + atomic work-stealing.
// 1280 blocks (5/CU, LDS = exactly 160KB/CU), 1024 items (qt 31..0 heavy-first) x 32 bh.
// Item broadcast reuses Ks[0] (no extra LDS). Inner loop = round-7 proven body.
__global__ __launch_bounds__(256) void attn_kernel(const unsigned short* __restrict__ Qh,
                                                   const unsigned short* __restrict__ Kh,
                                                   const unsigned short* __restrict__ Vtp,
                                                   unsigned short* __restrict__ AO,
                                                   unsigned int* __restrict__ ctr){
  __shared__ __align__(16) unsigned short Ks [128*64];   // 16 KB (also item bcast + O stage)
  __shared__ __align__(16) unsigned short Vts[64*128];   // 16 KB
  const int tid = threadIdx.x;
  const int lane = tid & 63, w = tid >> 6;   // 4 waves; wave w: q rows q0+w*16..+16
  const int quad = lane >> 4, c = lane & 15;
  const f32x4 z4 = {0.f, 0.f, 0.f, 0.f};

  for (;;){
    __syncthreads();                          // LDS quiet (prev item's writeout done)
    if (tid == 0) *(volatile unsigned int*)Ks = atomicAdd(ctr, 1u);
    __syncthreads();
    const unsigned int item = *(volatile unsigned int*)Ks;
    if (item >= 1024u) break;
    const int qt = 31 - (int)(item >> 5);     // heavy-first
    const int bh = (int)(item & 31u);
    const int h = bh >> 1, b = bh & 1;
    const int q0 = qt * 64;
    const size_t hb = (size_t)(h*2 + b) * 2048 * 64;
    const unsigned short* qp = Qh + hb;
    const unsigned short* kp = Kh + hb;
    const unsigned short* vp = Vtp + hb;

    bf16x8 qf[2];                             // Q fragments (B-operand layout)
    #pragma unroll
    for (int ks = 0; ks < 2; ks++)
      qf[ks] = *(const bf16x8*)&qp[(size_t)(q0 + w*16 + c)*64 + ks*32 + quad*8];

    float rs = 0.f;                           // per-lane row-sum (q = c), max-free
    f32x4 Oa[4];                              // O^T: lane holds O[d=dt*16+quad*4+r][q=c]
    #pragma unroll
    for (int dt = 0; dt < 4; dt++) Oa[dt] = z4;

    const int nkt = (qt >> 1) + 1;
    for (int kt = 0; kt < nkt; kt++){
      const int kv0 = kt * 128;
      const int qrel = (q0 + w*16 - kv0) >> 4;
      __syncthreads();
      #pragma unroll
      for (int p = 0; p < 4; p++){
        int blk = p*4 + w;
        int L = blk*64 + lane;
        {   // K tile: row = kv, 8 chunks of 8 along d, chunk XOR row&7
          int row = L >> 3;
          int sub = (L & 7) ^ (row & 7);
          gld16(&kp[(size_t)(kv0 + row)*64 + sub*8], &Ks[blk*512]);
        }
        {   // Vt tile: d rows, 16 chunks of 8 along kv~, chunk XOR d&15
          int d = L >> 4;
          int mp = (L & 15) ^ (d & 15);
          gld16(&vp[(size_t)d*2048 + kv0 + mp*8], &Vts[blk*512]);
        }
      }
      __syncthreads();

      #pragma unroll
      for (int hk = 0; hk < 2; hk++){
        const int rmask = qrel - hk*4;        // tile index where masking starts
        const int rlim  = (rmask < 3) ? rmask : 3;
        if (rlim < 0) continue;
        f32x4 sa[4];
        #pragma unroll
        for (int rt = 0; rt < 4; rt++) sa[rt] = z4;
        #pragma unroll
        for (int ks = 0; ks < 2; ks++)
          #pragma unroll
          for (int rt = 0; rt < 4; rt++){
            if (rt > rlim) continue;
            int row = hk*64 + rt*16 + c;
            int pos = (ks*4 + quad) ^ (c & 7);
            bf16x8 kf = *(const bf16x8*)&Ks[row*64 + pos*8];
            sa[rt] = __builtin_amdgcn_mfma_f32_16x16x32_bf16(kf, qf[ks], sa[rt], 0, 0, 0);
          }
        f32x4 psv[4];
        #pragma unroll
        for (int rt = 0; rt < 4; rt++) psv[rt] = z4;
        #pragma unroll
        for (int rt = 0; rt < 4; rt++){
          if (rt > rlim) continue;
          if (rt == rmask){                   // boundary 16x16: mask kv > q
            #pragma unroll
            for (int r = 0; r < 4; r++)
              sa[rt][r] = ((quad*4 + r) > c) ? -3.0e38f : sa[rt][r];
          }
          #pragma unroll
          for (int r = 0; r < 4; r++){
            float p = exp2f(sa[rt][r]);       // scale pre-folded into Q
            rs += p;
            psv[rt][r] = p;
          }
        }
        // PV in 32-kv chunks: pf8 = [psv[2ck] | psv[2ck+1]] matches pi-permuted Vts
        #pragma unroll
        for (int ck = 0; ck < 2; ck++){
          if (2*ck > rlim) continue;
          union { unsigned int u[4]; bf16x8 v; } pf;
          pf.u[0] = pack_bf2(psv[2*ck][0],   psv[2*ck][1]);
          pf.u[1] = pack_bf2(psv[2*ck][2],   psv[2*ck][3]);
          pf.u[2] = pack_bf2(psv[2*ck+1][0], psv[2*ck+1][1]);
          pf.u[3] = pack_bf2(psv[2*ck+1][2], psv[2*ck+1][3]);
          const int m8 = hk*8 + ck*4 + quad;  // chunk-of-8 index along kv~
          #pragma unroll
          for (int dt = 0; dt < 4; dt++){
            int d = dt*16 + c;
            int pos = m8 ^ c;                 // d & 15 == c
            bf16x8 vf = *(const bf16x8*)&Vts[d*128 + pos*8];
            Oa[dt] = __builtin_amdgcn_mfma_f32_16x16x32_bf16(vf, pf.v, Oa[dt], 0, 0, 0);
          }
        }
      }
    }
    rs += __shfl_xor(rs, 16, 64);
    rs += __shfl_xor(rs, 32, 64);
    float inv = __builtin_amdgcn_rcpf(rs);
    // stage O (bf16) into Ks as [s(64)][d(64)] xor-swizzled, then coalesced writeout
    __syncthreads();                          // all waves done with Ks/Vts
    #pragma unroll
    for (int dt = 0; dt < 4; dt++)
      #pragma unroll
      for (int r = 0; r < 4; r++){
        int srow = w*16 + c;                  // local s (lane's q)
        int d = dt*16 + quad*4 + r;
        Ks[srow*64 + (d ^ ((srow & 7) << 3))] = f2bf(Oa[dt][r] * inv);
      }
    __syncthreads();
    #pragma unroll
    for (int it = 0; it < 2; it++){
      int cidx = it*256 + tid;                // sl(64) x sub(8)
      int sl = cidx >> 3, sub = cidx & 7;
      u16x8 pk = *(const u16x8*)&Ks[sl*64 + ((sub*8) ^ ((sl & 7) << 3))];
      *(u16x8*)&AO[(size_t)(b*2048 + q0 + sl)*1024 + h*64 + sub*8] = pk;
    }
  }
}

extern "C" void kernel_launch(void* const* d_in, const int* in_sizes, int n_in,
                              void* d_out, int out_size, void* d_ws, size_t ws_size,
                              hipStream_t stream){
  const float* X    = (const float*)d_in[0];
  const float* Wqkv = (const float*)d_in[1];
  const float* Wo   = (const float*)d_in[2];
  float* out = (float*)d_out;
  char* ws = (char*)d_ws;
  unsigned short* Xb    = (unsigned short*)(ws);
  unsigned short* Wqkvb = (unsigned short*)(ws + (size_t)8  * 1048576);
  unsigned short* Wob   = (unsigned short*)(ws + (size_t)14 * 1048576);
  unsigned short* Qh    = (unsigned short*)(ws + (size_t)40 * 1048576);
  unsigned short* Kh    = (unsigned short*)(ws + (size_t)48 * 1048576);
  unsigned short* Vtp   = (unsigned short*)(ws + (size_t)56 * 1048576);
  unsigned short* AO    = (unsigned short*)(ws + (size_t)64 * 1048576);
  unsigned int*   ctr   = (unsigned int*)  (ws + (size_t)72 * 1048576);

  hipMemsetAsync(ctr, 0, 4, stream);
  cast3_kernel<<<8192, 256, 0, stream>>>(X, Wqkv, Wo, Xb, Wqkvb, Wob, 1048576, 786432);
  gemm_qkv<<<768, 256, 0, stream>>>(Xb, Wqkvb, Qh, Kh, Vtp);
  attn_kernel<<<1280, 256, 0, stream>>>(Qh, Kh, Vtp, AO, ctr);
  gemm_o<<<512, 256, 0, stream>>>(AO, Wob, out, 4096, 1024, 1024);
}

// Round 10
// 171.644 us; speedup vs baseline: 1.1720x; 1.1720x over previous
//
#include <hip/hip_runtime.h>
#include <stdint.h>

// B=2, S=2048, D=1024, H=16, dh=64, THETA=10000
// cast3 -> QKV gemm (XCD-swizzled, LDS-staged rope/vtrans epilogue) ->
// flash attn (BQ=64, static grid w/ bh-in-low-bits XCD locality, S^T, reg-PV,
//             1-instr exp2, rs via ones-MFMA) -> out gemm

typedef __attribute__((ext_vector_type(8))) __bf16 bf16x8;
typedef __attribute__((ext_vector_type(8))) unsigned short u16x8;
typedef __attribute__((ext_vector_type(4))) float f32x4;

__device__ __forceinline__ unsigned short f2bf(float f){
  unsigned int u = __float_as_uint(f);
  unsigned int r = (u + 0x7FFFu + ((u >> 16) & 1u)) >> 16;  // RNE
  return (unsigned short)r;
}
__device__ __forceinline__ float bf2f(unsigned short u){
  return __uint_as_float(((unsigned int)u) << 16);
}
// pack two fp32 -> two bf16 (truncate) in one v_perm_b32
__device__ __forceinline__ unsigned int pack_bf2(float lo, float hi){
  return __builtin_amdgcn_perm(__float_as_uint(hi), __float_as_uint(lo), 0x07060302u);
}
// single v_exp_f32 (libm exp2f may lower to a guarded multi-instr sequence)
__device__ __forceinline__ float fexp2(float x){
#if __has_builtin(__builtin_amdgcn_exp2f)
  return __builtin_amdgcn_exp2f(x);
#else
  return exp2f(x);
#endif
}

// async global->LDS, 16B per lane; LDS dest = wave-uniform base + lane*16
__device__ __forceinline__ void gld16(const unsigned short* g, unsigned short* l){
  __builtin_amdgcn_global_load_lds((const __attribute__((address_space(1))) unsigned int*)g,
                                   (__attribute__((address_space(3))) unsigned int*)l,
                                   16, 0, 0);
}

__global__ __launch_bounds__(256) void cast3_kernel(const float* __restrict__ a,
                                                    const float* __restrict__ b,
                                                    const float* __restrict__ c,
                                                    unsigned short* __restrict__ oa,
                                                    unsigned short* __restrict__ ob,
                                                    unsigned short* __restrict__ oc,
                                                    int na, int nb){
  int i = blockIdx.x * 256 + threadIdx.x;
  const float* in; unsigned short* out; int j = i;
  if (i < na){ in = a; out = oa; }
  else if (i < na + nb){ in = b; out = ob; j = i - na; }
  else { in = c; out = oc; j = i - na - nb; }
  float4 v = ((const float4*)in)[j];
  ushort4 o;
  o.x = f2bf(v.x); o.y = f2bf(v.y); o.z = f2bf(v.z); o.w = f2bf(v.w);
  ((ushort4*)out)[j] = o;
}

// QKV = X * Wqkv^T, 128x128 tile, BK=64, async-LDS, XOR swizzle.
// Grid: 768 blocks 1D; xcd = bx&7 owns n-tiles {3*xcd..3*xcd+2} (W hot in per-XCD L2).
__global__ __launch_bounds__(256) void gemm_qkv(const unsigned short* __restrict__ A,
                                                const unsigned short* __restrict__ W,
                                                unsigned short* __restrict__ Qh,
                                                unsigned short* __restrict__ Kh,
                                                unsigned short* __restrict__ Vtp){
  __shared__ __align__(16) unsigned short As[128*64];
  __shared__ __align__(16) unsigned short Bs[128*64];
  const int K = 1024;
  const int tid  = threadIdx.x;
  const int lane = tid & 63, wave = tid >> 6;
  const int wr = wave >> 1, wc = wave & 1;
  const int quad = lane >> 4, c = lane & 15;
  const int bx = blockIdx.x;
  const int xcd = bx & 7, kk = bx >> 3;       // kk in [0,96)
  const int n0 = (xcd*3 + (kk % 3)) * 128;
  const int m0 = (kk / 3) * 128;

  const f32x4 z4 = {0.f, 0.f, 0.f, 0.f};
  f32x4 acc[4][4];
  #pragma unroll
  for (int i = 0; i < 4; i++)
    #pragma unroll
    for (int j = 0; j < 4; j++) acc[i][j] = z4;

  for (int kt = 0; kt < 16; kt++){
    const int k0 = kt << 6;
    #pragma unroll
    for (int p = 0; p < 4; p++){
      int blk = p*4 + wave;
      int L = blk*64 + lane;
      int row = L >> 3;
      int sub = (L & 7) ^ (row & 7);
      gld16(&A[(size_t)(m0+row)*K + k0 + sub*8], &As[blk*512]);
      gld16(&W[(size_t)(n0+row)*K + k0 + sub*8], &Bs[blk*512]);
    }
    __syncthreads();
    #pragma unroll
    for (int ks = 0; ks < 2; ks++){
      bf16x8 af[4], bfr[4];
      #pragma unroll
      for (int i = 0; i < 4; i++){
        int row = wr*64 + i*16 + c;
        int pos = (ks*4 + quad) ^ (c & 7);
        af[i] = *(const bf16x8*)&As[row*64 + pos*8];
      }
      #pragma unroll
      for (int j = 0; j < 4; j++){
        int row = wc*64 + j*16 + c;
        int pos = (ks*4 + quad) ^ (c & 7);
        bfr[j] = *(const bf16x8*)&Bs[row*64 + pos*8];
      }
      #pragma unroll
      for (int i = 0; i < 4; i++)
        #pragma unroll
        for (int j = 0; j < 4; j++)
          acc[i][j] = __builtin_amdgcn_mfma_f32_16x16x32_bf16(af[i], bfr[j], acc[i][j], 0, 0, 0);
    }
    __syncthreads();
  }

  const int t  = n0 >> 10;            // 0=Q 1=K 2=V (block-uniform)
  const int h0 = (n0 & 1023) >> 6;
  const int bb = m0 >> 11;            // batch (tile never crosses the boundary)
  const int s0 = m0 & 2047;

  // stage C tile (each wave-column's 64 cols) into LDS, bf16, xor-swizzled
  unsigned short* stg = wc ? Bs : As;
  #pragma unroll
  for (int i = 0; i < 4; i++)
    #pragma unroll
    for (int j = 0; j < 4; j++)
      #pragma unroll
      for (int r = 0; r < 4; r++){
        int sl = wr*64 + i*16 + quad*4 + r;
        int d  = j*16 + c;
        stg[sl*64 + (d ^ ((sl & 7) << 3))] = f2bf(acc[i][j][r]);
      }
  __syncthreads();

  if (t < 2){
    // rope at readout: lane holds 8 consecutive d = 4 (even,odd) pairs in-register
    unsigned short* dst = (t == 0) ? Qh : Kh;
    const float qs = (t == 0) ? 0.18033688011112042f : 1.0f;   // log2(e)/8 into Q
    #pragma unroll
    for (int it = 0; it < 8; it++){
      int cidx2 = it*256 + tid;            // hh(2) x sl(128) x sub(8)
      int hh = cidx2 >> 10, cidx = cidx2 & 1023;
      int sl = cidx >> 3, sub = cidx & 7;
      const unsigned short* src = hh ? Bs : As;
      u16x8 pk = *(const u16x8*)&src[sl*64 + ((sub*8) ^ ((sl & 7) << 3))];
      int s = s0 + sl;
      u16x8 o;
      #pragma unroll
      for (int tp = 0; tp < 4; tp++){
        int p = sub*4 + tp;
        float freq = __expf(-(float)p * 0.28782313662425572f);  // theta^(-p/32)
        float ang = (float)s * freq;
        float sn, cs;
        __sincosf(ang, &sn, &cs);
        float e = bf2f(pk[2*tp]), od = bf2f(pk[2*tp+1]);
        o[2*tp]   = f2bf((e*cs - od*sn) * qs);
        o[2*tp+1] = f2bf((e*sn + od*cs) * qs);
      }
      *(u16x8*)&dst[(size_t)((h0 + hh)*2 + bb)*2048*64 + (size_t)s*64 + sub*8] = o;
    }
  } else {
    // V: transpose + pi-permute -> Vtp [h][b][d][S]
    #pragma unroll
    for (int it = 0; it < 8; it++){
      int cidx2 = it*256 + tid;             // hh(2) x d(64) x g8(16)
      int hh = cidx2 >> 10, cidx = cidx2 & 1023;
      int d = cidx >> 4, g8 = cidx & 15;
      int C = g8 >> 2, q8 = g8 & 3;
      const unsigned short* src = hh ? Bs : As;
      u16x8 pk;
      #pragma unroll
      for (int jj = 0; jj < 8; jj++){
        int r = C*32 + ((jj >> 2) << 4) + q8*4 + (jj & 3);   // pi
        pk[jj] = src[r*64 + (d ^ ((r & 7) << 3))];
      }
      size_t obase = (size_t)(((h0 + hh)*2 + bb) * 64) * 2048;
      *(u16x8*)&Vtp[obase + (size_t)d*2048 + s0 + g8*8] = pk;
    }
  }
}

// out gemm: 64M x 128N tile, fp32 out. xcd = bx&7 owns n-tile bx&7; m = bx>>3.
__global__ __launch_bounds__(256) void gemm_o(const unsigned short* __restrict__ A,
                                              const unsigned short* __restrict__ W,
                                              float* __restrict__ Cp,
                                              int M, int N, int K){
  __shared__ __align__(16) unsigned short As[64*64];
  __shared__ __align__(16) unsigned short Bs[128*64];
  const int tid  = threadIdx.x;
  const int lane = tid & 63, wave = tid >> 6;
  const int wr = wave >> 1, wc = wave & 1;
  const int quad = lane >> 4, c = lane & 15;
  const int m0 = (blockIdx.x >> 3) * 64, n0 = (blockIdx.x & 7) * 128;

  const f32x4 z4 = {0.f, 0.f, 0.f, 0.f};
  f32x4 acc[2][4];
  #pragma unroll
  for (int i = 0; i < 2; i++)
    #pragma unroll
    for (int j = 0; j < 4; j++) acc[i][j] = z4;

  const int nk = K >> 6;
  for (int kt = 0; kt < nk; kt++){
    const int k0 = kt << 6;
    #pragma unroll
    for (int p = 0; p < 2; p++){
      int blk = p*4 + wave;
      int L = blk*64 + lane;
      int row = L >> 3;
      int sub = (L & 7) ^ (row & 7);
      gld16(&A[(size_t)(m0+row)*K + k0 + sub*8], &As[blk*512]);
    }
    #pragma unroll
    for (int p = 0; p < 4; p++){
      int blk = p*4 + wave;
      int L = blk*64 + lane;
      int row = L >> 3;
      int sub = (L & 7) ^ (row & 7);
      gld16(&W[(size_t)(n0+row)*K + k0 + sub*8], &Bs[blk*512]);
    }
    __syncthreads();
    #pragma unroll
    for (int ks = 0; ks < 2; ks++){
      bf16x8 af[2], bfr[4];
      #pragma unroll
      for (int i = 0; i < 2; i++){
        int row = wr*32 + i*16 + c;
        int pos = (ks*4 + quad) ^ (c & 7);
        af[i] = *(const bf16x8*)&As[row*64 + pos*8];
      }
      #pragma unroll
      for (int j = 0; j < 4; j++){
        int row = wc*64 + j*16 + c;
        int pos = (ks*4 + quad) ^ (c & 7);
        bfr[j] = *(const bf16x8*)&Bs[row*64 + pos*8];
      }
      #pragma unroll
      for (int i = 0; i < 2; i++)
        #pragma unroll
        for (int j = 0; j < 4; j++)
          acc[i][j] = __builtin_amdgcn_mfma_f32_16x16x32_bf16(af[i], bfr[j], acc[i][j], 0, 0, 0);
    }
    __syncthreads();
  }
  #pragma unroll
  for (int i = 0; i < 2; i++)
    #pragma unroll
    for (int j = 0; j < 4; j++)
      #pragma unroll
      for (int r = 0; r < 4; r++){
        int row = m0 + wr*32 + i*16 + quad*4 + r;
        int col = n0 + wc*64 + j*16 + c;
        Cp[(size_t)row*N + col] = acc[i][j][r];
      }
}

// Flash attention, causal, S^T. BQ=64 (4 waves x 16 q), BKV=128.
// Static 1024-block grid; bh in low 5 bits -> per-XCD L2 keeps its 4 (h,b) K/V sets hot.
// qt pairing: g and g+16 sum to 17 iters per CU pair. exp2 = 1 instr; rs via ones-MFMA.
__global__ __launch_bounds__(256, 4) void attn_kernel(const unsigned short* __restrict__ Qh,
                                                      const unsigned short* __restrict__ Kh,
                                                      const unsigned short* __restrict__ Vtp,
                                                      unsigned short* __restrict__ AO){
  __shared__ __align__(16) unsigned short Ks [128*64];   // 16 KB (also O-stage)
  __shared__ __align__(16) unsigned short Vts[64*128];   // 16 KB
  const int bx = blockIdx.x;                 // 1024 = 32 g x 32 bh
  const int g  = bx >> 5;
  const int qt = (g < 16) ? (31 - g) : (g - 16);
  const int bh = bx & 31;
  const int h = bh >> 1, b = bh & 1;
  const int q0 = qt * 64;
  const int tid = threadIdx.x;
  const int lane = tid & 63, w = tid >> 6;   // 4 waves; wave w: q rows q0+w*16..+16
  const int quad = lane >> 4, c = lane & 15;
  const size_t hb = (size_t)(h*2 + b) * 2048 * 64;
  const unsigned short* qp = Qh + hb;
  const unsigned short* kp = Kh + hb;
  const unsigned short* vp = Vtp + hb;

  bf16x8 qf[2];                               // Q fragments (B-operand layout)
  #pragma unroll
  for (int ks = 0; ks < 2; ks++)
    qf[ks] = *(const bf16x8*)&qp[(size_t)(q0 + w*16 + c)*64 + ks*32 + quad*8];

  union { unsigned int u[4]; bf16x8 v; } ones;
  ones.u[0] = ones.u[1] = ones.u[2] = ones.u[3] = 0x3F803F80u;   // bf16 1.0 x8

  const f32x4 z4 = {0.f, 0.f, 0.f, 0.f};
  f32x4 rsa = z4;                             // row-sum accumulator (MFMA pipe)
  f32x4 Oa[4];                                // O^T: lane holds O[d=dt*16+quad*4+r][q=c]
  #pragma unroll
  for (int dt = 0; dt < 4; dt++) Oa[dt] = z4;

  const int nkt = (qt >> 1) + 1;
  for (int kt = 0; kt < nkt; kt++){
    const int kv0 = kt * 128;
    const int qrel = (q0 + w*16 - kv0) >> 4;  // wave's q-tile index rel. to kv tile
    __syncthreads();
    #pragma unroll
    for (int p = 0; p < 4; p++){
      int blk = p*4 + w;
      int L = blk*64 + lane;
      {   // K tile: row = kv, 8 chunks of 8 along d, chunk XOR row&7
        int row = L >> 3;
        int sub = (L & 7) ^ (row & 7);
        gld16(&kp[(size_t)(kv0 + row)*64 + sub*8], &Ks[blk*512]);
      }
      {   // Vt tile: d rows, 16 chunks of 8 along kv~, chunk XOR d&15
        int d = L >> 4;
        int mp = (L & 15) ^ (d & 15);
        gld16(&vp[(size_t)d*2048 + kv0 + mp*8], &Vts[blk*512]);
      }
    }
    __syncthreads();

    #pragma unroll
    for (int hk = 0; hk < 2; hk++){
      const int rmask = qrel - hk*4;          // tile index where masking starts
      const int rlim  = (rmask < 3) ? rmask : 3;   // wave-uniform causal tile skip
      if (rlim < 0) continue;
      f32x4 sa[4];
      #pragma unroll
      for (int rt = 0; rt < 4; rt++) sa[rt] = z4;
      #pragma unroll
      for (int ks = 0; ks < 2; ks++)
        #pragma unroll
        for (int rt = 0; rt < 4; rt++){
          if (rt > rlim) continue;
          int row = hk*64 + rt*16 + c;
          int pos = (ks*4 + quad) ^ (c & 7);
          bf16x8 kf = *(const bf16x8*)&Ks[row*64 + pos*8];
          sa[rt] = __builtin_amdgcn_mfma_f32_16x16x32_bf16(kf, qf[ks], sa[rt], 0, 0, 0);
        }
      f32x4 psv[4];
      #pragma unroll
      for (int rt = 0; rt < 4; rt++) psv[rt] = z4;
      #pragma unroll
      for (int rt = 0; rt < 4; rt++){
        if (rt > rlim) continue;
        if (rt == rmask){                     // boundary 16x16: mask kv > q
          #pragma unroll
          for (int r = 0; r < 4; r++)
            sa[rt][r] = ((quad*4 + r) > c) ? -3.0e38f : sa[rt][r];
        }
        #pragma unroll
        for (int r = 0; r < 4; r++)
          psv[rt][r] = fexp2(sa[rt][r]);      // scale pre-folded into Q; 1 v_exp_f32
      }
      // PV in 32-kv chunks: pf8 = [psv[2ck] | psv[2ck+1]] matches pi-permuted Vts
      #pragma unroll
      for (int ck = 0; ck < 2; ck++){
        if (2*ck > rlim) continue;
        union { unsigned int u[4]; bf16x8 v; } pf;
        pf.u[0] = pack_bf2(psv[2*ck][0],   psv[2*ck][1]);
        pf.u[1] = pack_bf2(psv[2*ck][2],   psv[2*ck][3]);
        pf.u[2] = pack_bf2(psv[2*ck+1][0], psv[2*ck+1][1]);
        pf.u[3] = pack_bf2(psv[2*ck+1][2], psv[2*ck+1][3]);
        rsa = __builtin_amdgcn_mfma_f32_16x16x32_bf16(ones.v, pf.v, rsa, 0, 0, 0);
        const int m8 = hk*8 + ck*4 + quad;    // chunk-of-8 index along kv~
        #pragma unroll
        for (int dt = 0; dt < 4; dt++){
          int d = dt*16 + c;
          int pos = m8 ^ c;                   // d & 15 == c
          bf16x8 vf = *(const bf16x8*)&Vts[d*128 + pos*8];
          Oa[dt] = __builtin_amdgcn_mfma_f32_16x16x32_bf16(vf, pf.v, Oa[dt], 0, 0, 0);
        }
      }
    }
  }
  float inv = __builtin_amdgcn_rcpf(rsa[0]);  // every rsa row holds the full row-sum
  // stage O (bf16) into Ks as [s(64)][d(64)] xor-swizzled, then coalesced writeout
  __syncthreads();                            // all waves done with Ks/Vts
  #pragma unroll
  for (int dt = 0; dt < 4; dt++)
    #pragma unroll
    for (int r = 0; r < 4; r++){
      int srow = w*16 + c;                    // local s (lane's q)
      int d = dt*16 + quad*4 + r;
      Ks[srow*64 + (d ^ ((srow & 7) << 3))] = f2bf(Oa[dt][r] * inv);
    }
  __syncthreads();
  #pragma unroll
  for (int it = 0; it < 2; it++){
    int cidx = it*256 + tid;                  // sl(64) x sub(8)
    int sl = cidx >> 3, sub = cidx & 7;
    u16x8 pk = *(const u16x8*)&Ks[sl*64 + ((sub*8) ^ ((sl & 7) << 3))];
    *(u16x8*)&AO[(size_t)(b*2048 + q0 + sl)*1024 + h*64 + sub*8] = pk;
  }
}

extern "C" void kernel_launch(void* const* d_in, const int* in_sizes, int n_in,
                              void* d_out, int out_size, void* d_ws, size_t ws_size,
                              hipStream_t stream){
  const float* X    = (const float*)d_in[0];
  const float* Wqkv = (const float*)d_in[1];
  const float* Wo   = (const float*)d_in[2];
  float* out = (float*)d_out;
  char* ws = (char*)d_ws;
  unsigned short* Xb    = (unsigned short*)(ws);
  unsigned short* Wqkvb = (unsigned short*)(ws + (size_t)8  * 1048576);
  unsigned short* Wob   = (unsigned short*)(ws + (size_t)14 * 1048576);
  unsigned short* Qh    = (unsigned short*)(ws + (size_t)40 * 1048576);
  unsigned short* Kh    = (unsigned short*)(ws + (size_t)48 * 1048576);
  unsigned short* Vtp   = (unsigned short*)(ws + (size_t)56 * 1048576);
  unsigned short* AO    = (unsigned short*)(ws + (size_t)64 * 1048576);

  cast3_kernel<<<8192, 256, 0, stream>>>(X, Wqkv, Wo, Xb, Wqkvb, Wob, 1048576, 786432);
  gemm_qkv<<<768, 256, 0, stream>>>(Xb, Wqkvb, Qh, Kh, Vtp);
  attn_kernel<<<1024, 256, 0, stream>>>(Qh, Kh, Vtp, AO);
  gemm_o<<<512, 256, 0, stream>>>(AO, Wob, out, 4096, 1024, 1024);
}